// Round 7
// baseline (135.333 us; speedup 1.0000x reference)
//
#include <hip/hip_runtime.h>

// out[m][e*5+c] = x[m,c]*w_c[e] + (b_c[e] + ot[c][e]);  M=65536, E=512
// Pure HBM-write-bound (640 MiB f32 out). Ladder:
//   R1 136us: barrier-per-2-rows LDS copy                    ~4.9 TB/s
//   R2 242us: global x loads share in-order vmcnt with stores
//   R4 131us: pure store stream, no barriers in loop         ~5.1 TB/s
//   R5 134us: persistent blocks, zero tail skew, lgkm-only barriers
//   R6: compile error (__builtin_nontemporal_store rejects HIP_vector_type;
//       needs a native clang ext_vector_type)
// R7 = R4 byte-identical EXCEPT stores are nontemporal (global_store nt) via
// ext_vector float4. Tests: L2 write-allocate churn as the residual limiter.

#define ROWS 32
#define THREADS 640            // 10 waves; one float4 output slot per thread

typedef float f32x4 __attribute__((ext_vector_type(4)));

__global__ __launch_bounds__(THREADS) void pc_kernel(
    const float* __restrict__ x,
    const float* __restrict__ w_bet,  const float* __restrict__ b_bet,
    const float* __restrict__ w_stk,  const float* __restrict__ b_stk,
    const float* __restrict__ w_call, const float* __restrict__ b_call,
    const float* __restrict__ w_odds, const float* __restrict__ b_odds,
    const float* __restrict__ ot,
    float* __restrict__ out)
{
    __shared__ float tw[2560];          // tw[c*512+e] = w_c[e]
    __shared__ float tb[2560];          // tb[c*512+e] = b_c[e] + ot[c][e]
    __shared__ float xl[ROWS * 5];      // block's x slice (160 floats)

    const int tid = threadIdx.x;

    // ---- one-time staging (the only barrier in the kernel) ----
    {
        const int c  = tid >> 7;        // 0..4
        const int e0 = (tid & 127) * 4;
        const float* wp; const float* bp;
        if      (c == 0) { wp = w_bet;  bp = b_bet;  }
        else if (c == 1) { wp = w_stk;  bp = b_stk;  }
        else if (c == 2) { wp = w_stk;  bp = b_stk;  }
        else if (c == 3) { wp = w_call; bp = b_call; }
        else             { wp = w_odds; bp = b_odds; }
        float4 w4 = *reinterpret_cast<const float4*>(wp + e0);
        float4 b4 = *reinterpret_cast<const float4*>(bp + e0);
        float4 o4 = *reinterpret_cast<const float4*>(ot + c * 512 + e0);
        *reinterpret_cast<float4*>(tw + c * 512 + e0) = w4;
        float4 bb;
        bb.x = b4.x + o4.x; bb.y = b4.y + o4.y;
        bb.z = b4.z + o4.z; bb.w = b4.w + o4.w;
        *reinterpret_cast<float4*>(tb + c * 512 + e0) = bb;

        if (tid < ROWS * 5 / 4)         // 40 threads stage the x slice
            reinterpret_cast<float4*>(xl)[tid] =
                reinterpret_cast<const float4*>(x)[blockIdx.x * (ROWS * 5 / 4) + tid];
    }
    __syncthreads();

    // ---- per-thread row-invariant table values for output words 4t..4t+3 ----
    float wv[4], bv[4];
    int   cj[4];
#pragma unroll
    for (int j = 0; j < 4; ++j) {
        int w = 4 * tid + j;            // word within a row, 0..2559
        int e = w / 5;                  // magic-mul (setup only)
        int c = w - 5 * e;
        cj[j] = c;
        wv[j] = tw[c * 512 + e];
        bv[j] = tb[c * 512 + e];
    }

    const int m_base = blockIdx.x * ROWS;
    f32x4* outv = reinterpret_cast<f32x4*>(out);
    const size_t obase = (size_t)m_base * 640 + tid;

#pragma unroll 8
    for (int r = 0; r < ROWS; ++r) {
        const float* xr = xl + r * 5;   // LDS row (lgkmcnt path, broadcast)
        f32x4 v;
        v.x = fmaf(xr[cj[0]], wv[0], bv[0]);
        v.y = fmaf(xr[cj[1]], wv[1], bv[1]);
        v.z = fmaf(xr[cj[2]], wv[2], bv[2]);
        v.w = fmaf(xr[cj[3]], wv[3], bv[3]);
        // nontemporal: global_store_dwordx4 ... nt (no L2 allocate)
        __builtin_nontemporal_store(v, &outv[obase + (size_t)r * 640]);
    }
}

extern "C" void kernel_launch(void* const* d_in, const int* in_sizes, int n_in,
                              void* d_out, int out_size, void* d_ws, size_t ws_size,
                              hipStream_t stream) {
    const float* x      = (const float*)d_in[0];
    const float* w_bet  = (const float*)d_in[1];
    const float* b_bet  = (const float*)d_in[2];
    const float* w_stk  = (const float*)d_in[3];
    const float* b_stk  = (const float*)d_in[4];
    const float* w_call = (const float*)d_in[5];
    const float* b_call = (const float*)d_in[6];
    const float* w_odds = (const float*)d_in[7];
    const float* b_odds = (const float*)d_in[8];
    const float* ot     = (const float*)d_in[9];
    float* out = (float*)d_out;

    const int M    = in_sizes[0] / 5;   // 65536
    const int grid = M / ROWS;          // 2048 blocks

    pc_kernel<<<grid, THREADS, 0, stream>>>(x, w_bet, b_bet, w_stk, b_stk,
                                            w_call, b_call, w_odds, b_odds,
                                            ot, out);
}

// Round 8
// 131.578 us; speedup vs baseline: 1.0285x; 1.0285x over previous
//
#include <hip/hip_runtime.h>

// out[m][e*5+c] = x[m,c]*w_c[e] + (b_c[e] + ot[c][e]);  M=65536, E=512
// Pure HBM-write-bound (671 MB f32 out). Ladder:
//   R1 136us barrier-heavy | R2 242us vmcnt mixing | R4 131us pure stream
//   R5 134us persistent/no-skew | R7 135us nontemporal
// All schedule/cache variants cluster 131-136us (~5.1 TB/s) vs fill 6.7 TB/s.
// Only unvaried dimension: per-wave store RUN LENGTH (always 1 KB chunks with
// 10KB..5MB jumps; jump distance proved irrelevant R4-vs-R5). R8: each wave
// writes an 80 KB contiguous ascending stream (8 whole rows, 10 sequential
// 1KB stores per row). Tables therefore come from LDS (output-interleaved
// float4 tables, conflict-free ds_read_b128, offsets fold to immediates);
// x is 2x-replicated in LDS so the %5 column index needs no wrap.
//   grid 1024 = exactly 4 blocks/CU, 32 waves/CU, zero tail skew.

#define THREADS 512
#define RB      64            // rows per block; wave owns 8 consecutive rows
#define GRID    1024          // 65536 / RB

typedef float f32x4 __attribute__((ext_vector_type(4)));

__global__ __launch_bounds__(THREADS) void pc_kernel(
    const float* __restrict__ x,
    const float* __restrict__ w_bet,  const float* __restrict__ b_bet,
    const float* __restrict__ w_stk,  const float* __restrict__ b_stk,
    const float* __restrict__ w_call, const float* __restrict__ b_call,
    const float* __restrict__ w_odds, const float* __restrict__ b_odds,
    const float* __restrict__ ot,
    float* __restrict__ out)
{
    __shared__ f32x4 wt4[640];        // wt4[q][j] = w_{c}[e] for word 4q+j
    __shared__ f32x4 bt4[640];        // bt4[q][j] = b_c[e] + ot[c][e]
    __shared__ float xl2[RB][10];     // x rows, 2x replicated (mod-free index)

    const int tid = threadIdx.x;
    const int wv  = tid >> 6;         // wave 0..7
    const int ln  = tid & 63;
    const int m_base = blockIdx.x * RB;

    // ---- prologue: build output-interleaved tables in LDS ----
    for (int q = tid; q < 640; q += THREADS) {
        float wq_[4], bq_[4];
#pragma unroll
        for (int j = 0; j < 4; ++j) {
            int word = 4 * q + j;
            int e = word / 5;         // magic-mul div (prologue only)
            int c = word - 5 * e;
            float wvv, bvv;
            if      (c == 0) { wvv = w_bet[e];  bvv = b_bet[e];  }
            else if (c == 1) { wvv = w_stk[e];  bvv = b_stk[e];  }
            else if (c == 2) { wvv = w_stk[e];  bvv = b_stk[e];  }
            else if (c == 3) { wvv = w_call[e]; bvv = b_call[e]; }
            else             { wvv = w_odds[e]; bvv = b_odds[e]; }
            wq_[j] = wvv;
            bq_[j] = bvv + ot[c * 512 + e];
        }
        f32x4 a, b;
        a.x = wq_[0]; a.y = wq_[1]; a.z = wq_[2]; a.w = wq_[3];
        b.x = bq_[0]; b.y = bq_[1]; b.z = bq_[2]; b.w = bq_[3];
        wt4[q] = a;  bt4[q] = b;
    }
    // ---- prologue: x slice, 2x replicated ----
    for (int i = tid; i < RB * 10; i += THREADS) {
        int row = i / 10, k = i - 10 * row;
        int c = (k < 5) ? k : k - 5;
        xl2[row][k] = x[(size_t)(m_base + row) * 5 + c];
    }
    __syncthreads();                  // the only barrier

    // column class of word 4*ln+j: c0j = (4*ln + j) % 5 (row-invariant)
    const int c00 = (4 * ln)     % 5;
    const int c01 = (4 * ln + 1) % 5;
    const int c02 = (4 * ln + 2) % 5;
    const int c03 = (4 * ln + 3) % 5;

    f32x4* out4 = reinterpret_cast<f32x4*>(out);

    // wave wv owns rows m_base+8*wv .. +7 : 80 KB contiguous ascending
    for (int r = 0; r < 8; ++r) {
        const int mrow = 8 * wv + r;
        const int m    = m_base + mrow;
        const float* xr = &xl2[mrow][0];
        const size_t obase = (size_t)m * 640 + ln;
#pragma unroll
        for (int p = 0; p < 10; ++p) {
            const int q = p * 64 + ln;
            f32x4 wq = wt4[q];        // ds_read_b128, conflict-free
            f32x4 bq = bt4[q];        //   (imm-offset 1024*p folds in)
            const int d = p % 5;      // literal after unroll
            // word 4q+j has c = (c0j + d) % 5 ; xl2 replication absorbs wrap
            f32x4 v;
            v.x = fmaf(xr[c00 + d], wq.x, bq.x);
            v.y = fmaf(xr[c01 + d], wq.y, bq.y);
            v.z = fmaf(xr[c02 + d], wq.z, bq.z);
            v.w = fmaf(xr[c03 + d], wq.w, bq.w);
            out4[obase + p * 64] = v; // sequential 1 KB wave-stores, ascending
        }
    }
}

extern "C" void kernel_launch(void* const* d_in, const int* in_sizes, int n_in,
                              void* d_out, int out_size, void* d_ws, size_t ws_size,
                              hipStream_t stream) {
    const float* x      = (const float*)d_in[0];
    const float* w_bet  = (const float*)d_in[1];
    const float* b_bet  = (const float*)d_in[2];
    const float* w_stk  = (const float*)d_in[3];
    const float* b_stk  = (const float*)d_in[4];
    const float* w_call = (const float*)d_in[5];
    const float* b_call = (const float*)d_in[6];
    const float* w_odds = (const float*)d_in[7];
    const float* b_odds = (const float*)d_in[8];
    const float* ot     = (const float*)d_in[9];
    float* out = (float*)d_out;

    pc_kernel<<<GRID, THREADS, 0, stream>>>(x, w_bet, b_bet, w_stk, b_stk,
                                            w_call, b_call, w_odds, b_odds,
                                            ot, out);
}